// Round 3
// baseline (6998.931 us; speedup 1.0000x reference)
//
#include <hip/hip_runtime.h>
#include <cstdint>
#include <cstddef>

// RGCN 2-layer forward, MI355X round-1 baseline (resubmit; broker timeouts x2).
// Design: per-relation aggregation passes so agg is [N,128] (51.2 MB, L3-resident)
// instead of [N,8,128] (409.6 MB, HBM-bound). cnt computed once (shared graph).
// Root/bias/relu folded into GEMM epilogues. GEMM pass re-zeroes agg for the next
// scatter (ZERO template flag) to avoid separate memset launches.
// fp32 vector GEMM this round (correctness first); MFMA bf16 is the round-2 lever.

#define DIN 128
#define NREL 8

__global__ void zero_kernel(float4* __restrict__ p, int n4) {
  int i = blockIdx.x * blockDim.x + threadIdx.x;
  int stride = gridDim.x * blockDim.x;
  float4 z; z.x = z.y = z.z = z.w = 0.f;
  for (; i < n4; i += stride) p[i] = z;
}

__global__ void count_kernel(const int* __restrict__ tgt, const int* __restrict__ et,
                             int* __restrict__ cnt, int E) {
  int i = blockIdx.x * blockDim.x + threadIdx.x;
  int stride = gridDim.x * blockDim.x;
  for (; i < E; i += stride)
    atomicAdd(&cnt[tgt[i] * NREL + et[i]], 1);
}

// One 32-thread group per edge; each thread handles 4 contiguous floats (float4
// gather is coalesced per half-wave). Edges not matching `rel` are skipped
// (uniform across the group -> no divergence inside the group).
__global__ void scatter_kernel(const float* __restrict__ X, const int* __restrict__ src,
                               const int* __restrict__ tgt, const int* __restrict__ et,
                               float* __restrict__ agg, int E, int rel) {
  int g = (blockIdx.x * blockDim.x + threadIdx.x) >> 5;
  int lane = threadIdx.x & 31;
  int ngroups = (gridDim.x * blockDim.x) >> 5;
  for (int e = g; e < E; e += ngroups) {
    if (et[e] != rel) continue;
    int s = src[e], t = tgt[e];
    float4 v = *(const float4*)(X + (size_t)s * DIN + lane * 4);
    float* dst = agg + (size_t)t * DIN + lane * 4;
    atomicAdd(dst + 0, v.x);
    atomicAdd(dst + 1, v.y);
    atomicAdd(dst + 2, v.z);
    atomicAdd(dst + 3, v.w);
  }
}

// C[nrows,DOUT] (+)= scale_row(A[nrows,128]) * W[128,DOUT]
// scale_row = 1/max(cnt[row*8+rel],1) when cnt != nullptr, else 1.
// INIT: C = bias + A*W (first pass).  RELU: applied after the final += (last pass).
// ZERO: zero the consumed A rows afterwards (prepares agg for next scatter).
// Block = 256 threads, 64-row tile, full DOUT. A staged transposed in LDS
// (padded stride 68 -> conflict-free b128 reads), W staged in LDS (pad +4).
template <int DOUT, bool INIT, bool RELU, bool ZERO>
__launch_bounds__(256)
__global__ void gemm_acc(const float* __restrict__ A, float* __restrict__ Amut,
                         const float* __restrict__ W, const float* __restrict__ bias,
                         const int* __restrict__ cnt, int rel,
                         float* __restrict__ out, int nrows) {
  __shared__ float Bs[DIN][DOUT + 4];
  __shared__ float As[DIN][68];
  const int tid = threadIdx.x;

  // stage W
  #pragma unroll
  for (int i = 0; i < (DIN * DOUT) / (256 * 4); ++i) {
    int idx = (tid + i * 256) * 4;
    float4 w = *(const float4*)(W + idx);
    int k = idx / DOUT, d = idx % DOUT;
    *(float4*)&Bs[k][d] = w;
  }

  const int row0 = blockIdx.x * 64;
  const int arow = row0 + (tid >> 2);
  const int k0 = (tid & 3) * 32;  // each thread loads 32 floats of one row
  if (arow < nrows) {
    float scale = 1.0f;
    if (cnt != nullptr) scale = 1.0f / fmaxf((float)cnt[arow * NREL + rel], 1.0f);
    const float* ap = A + (size_t)arow * DIN + k0;
    #pragma unroll
    for (int kk = 0; kk < 32; kk += 4) {
      float4 a = *(const float4*)(ap + kk);
      As[k0 + kk + 0][tid >> 2] = a.x * scale;
      As[k0 + kk + 1][tid >> 2] = a.y * scale;
      As[k0 + kk + 2][tid >> 2] = a.z * scale;
      As[k0 + kk + 3][tid >> 2] = a.w * scale;
    }
    if (ZERO) {
      float4 z; z.x = z.y = z.z = z.w = 0.f;
      float* zp = Amut + (size_t)arow * DIN + k0;
      #pragma unroll
      for (int kk = 0; kk < 32; kk += 4) *(float4*)(zp + kk) = z;
    }
  } else {
    #pragma unroll
    for (int kk = 0; kk < 32; ++kk) As[k0 + kk][tid >> 2] = 0.f;
  }
  __syncthreads();

  constexpr int CPT = DOUT / 16;  // cols per thread: 8 (DOUT=128) or 4 (DOUT=64)
  float acc[4][CPT] = {};
  const int trow = tid >> 4, tcol = tid & 15;
  const float* asp = &As[0][trow * 4];
  const float* bsp = &Bs[0][tcol * CPT];

  #pragma unroll 4
  for (int k = 0; k < DIN; ++k) {
    float4 av = *(const float4*)(asp + k * 68);
    float a0 = av.x, a1 = av.y, a2 = av.z, a3 = av.w;
    float b[CPT];
    const float* bp = bsp + k * (DOUT + 4);
    float4 bv = *(const float4*)bp;
    b[0] = bv.x; b[1] = bv.y; b[2] = bv.z; b[3] = bv.w;
    if constexpr (CPT == 8) {
      float4 bv2 = *(const float4*)(bp + 4);
      b[4] = bv2.x; b[5] = bv2.y; b[6] = bv2.z; b[7] = bv2.w;
    }
    #pragma unroll
    for (int j = 0; j < CPT; ++j) {
      acc[0][j] += a0 * b[j];
      acc[1][j] += a1 * b[j];
      acc[2][j] += a2 * b[j];
      acc[3][j] += a3 * b[j];
    }
  }

  const int c0 = tcol * CPT;
  #pragma unroll
  for (int i = 0; i < 4; ++i) {
    int r = row0 + trow * 4 + i;
    if (r >= nrows) continue;
    float* orow = out + (size_t)r * DOUT + c0;
    #pragma unroll
    for (int j4 = 0; j4 < CPT; j4 += 4) {
      float4 o;
      if (INIT) o = *(const float4*)(bias + c0 + j4);
      else      o = *(const float4*)(orow + j4);
      o.x += acc[i][j4 + 0]; o.y += acc[i][j4 + 1];
      o.z += acc[i][j4 + 2]; o.w += acc[i][j4 + 3];
      if (RELU) {
        o.x = fmaxf(o.x, 0.f); o.y = fmaxf(o.y, 0.f);
        o.z = fmaxf(o.z, 0.f); o.w = fmaxf(o.w, 0.f);
      }
      *(float4*)(orow + j4) = o;
    }
  }
}

extern "C" void kernel_launch(void* const* d_in, const int* in_sizes, int n_in,
                              void* d_out, int out_size, void* d_ws, size_t ws_size,
                              hipStream_t stream) {
  const float* x     = (const float*)d_in[0];
  const int*   ei    = (const int*)d_in[1];
  const int*   et    = (const int*)d_in[2];
  const float* W1    = (const float*)d_in[3];
  const float* root1 = (const float*)d_in[4];
  const float* b1    = (const float*)d_in[5];
  const float* W2    = (const float*)d_in[6];
  const float* root2 = (const float*)d_in[7];
  const float* b2    = (const float*)d_in[8];
  float* out = (float*)d_out;

  const int N = in_sizes[0] / DIN;
  const int E = in_sizes[1] / 2;
  const int* src = ei;
  const int* tgt = ei + E;

  // workspace: cnt [N*8] int | agg [N*128] f32 | h [N*128] f32  (~105.6 MB)
  char* ws = (char*)d_ws;
  int*   cnt = (int*)ws;
  float* agg = (float*)(ws + (size_t)N * NREL * 4);
  float* h   = agg + (size_t)N * DIN;

  const int gb = (N + 63) / 64;  // GEMM blocks (64-row tiles)

  // zero cnt + agg (ws is re-poisoned 0xAA before every timed call)
  zero_kernel<<<2048, 256, 0, stream>>>((float4*)cnt, N * 2);
  zero_kernel<<<2048, 256, 0, stream>>>((float4*)agg, N * 32);
  count_kernel<<<2048, 256, 0, stream>>>(tgt, et, cnt, E);

  // ---- layer 1: h = relu(x@root1 + b1 + sum_r mean_r @ W1_r) ----
  gemm_acc<128, true, false, false><<<gb, 256, 0, stream>>>(
      x, nullptr, root1, b1, nullptr, 0, h, N);
  for (int r = 0; r < NREL; ++r) {
    scatter_kernel<<<4096, 256, 0, stream>>>(x, src, tgt, et, agg, E, r);
    const float* Wr = W1 + (size_t)r * DIN * DIN;
    if (r < 7)
      gemm_acc<128, false, false, true><<<gb, 256, 0, stream>>>(
          agg, agg, Wr, nullptr, cnt, r, h, N);
    else
      gemm_acc<128, false, true, true><<<gb, 256, 0, stream>>>(
          agg, agg, Wr, nullptr, cnt, r, h, N);  // RELU on final accumulate
  }

  // ---- layer 2: out = h@root2 + b2 + sum_r mean_r @ W2_r ----
  gemm_acc<64, true, false, false><<<gb, 256, 0, stream>>>(
      h, nullptr, root2, b2, nullptr, 0, out, N);
  for (int r = 0; r < NREL; ++r) {
    scatter_kernel<<<4096, 256, 0, stream>>>(h, src, tgt, et, agg, E, r);
    const float* Wr = W2 + (size_t)r * DIN * 64;
    if (r < 7)
      gemm_acc<64, false, false, true><<<gb, 256, 0, stream>>>(
          agg, agg, Wr, nullptr, cnt, r, out, N);
    else
      gemm_acc<64, false, false, false><<<gb, 256, 0, stream>>>(
          agg, nullptr, Wr, nullptr, cnt, r, out, N);
  }
}

// Round 7
// 1266.738 us; speedup vs baseline: 5.5252x; 5.5252x over previous
//
#include <hip/hip_runtime.h>
#include <cstdint>
#include <cstddef>

// RGCN 2-layer forward, round 5 resubmit (broker timeout; never ran) + __align__(16)
// on LDS arrays (bf16x8 access requires 16B alignment; base alignment was UB).
// CSR aggregation (round-4 logic) + bf16 MFMA GEMMs. Evidence r3: scatter atomics
// 5.76ms (400MB WRITE/pass RMW thrash) + fp32 GEMMs 1.13ms. CSR kills atomics;
// MFMA kills GEMM cost. Weights pre-transposed to WtT[9][DOUT][128] bf16 (panel 8 =
// root). fp32 accumulation in h/out via RMW epilogue. C/D mapping m89-verified;
// A/B frags share one lane formula so k-permutation uncertainty cancels.

#define DIN 128
#define NREL 8
#define SCAN_BLK 256
#define SCAN_ITEMS 16
#define SCAN_CHUNK (SCAN_BLK * SCAN_ITEMS)

typedef short bf16x8 __attribute__((ext_vector_type(8)));
typedef float f32x4 __attribute__((ext_vector_type(4)));

__device__ inline float bf2f(short s) {
  return __uint_as_float(((unsigned int)(unsigned short)s) << 16);
}
__device__ inline short f2bf(float f) {  // RTNE
  unsigned int u = __float_as_uint(f);
  unsigned int r = (u + 0x7FFFu + ((u >> 16) & 1u)) >> 16;
  return (short)r;
}

// ---------------- CSR build (unchanged from round 4) ----------------
__global__ void zero_ints(int4* __restrict__ p, int n4) {
  int i = blockIdx.x * blockDim.x + threadIdx.x;
  int stride = gridDim.x * blockDim.x;
  int4 z; z.x = z.y = z.z = z.w = 0;
  for (; i < n4; i += stride) p[i] = z;
}

__global__ void hist_kernel(const int* __restrict__ tgt, const int* __restrict__ et,
                            int* __restrict__ hist, int E, int N) {
  int i = blockIdx.x * blockDim.x + threadIdx.x;
  int stride = gridDim.x * blockDim.x;
  for (; i < E; i += stride)
    atomicAdd(&hist[et[i] * N + tgt[i]], 1);
}

__global__ void scanA(const int* __restrict__ hist, int* __restrict__ partials, int RN) {
  __shared__ int sh[SCAN_BLK];
  const int tid = threadIdx.x;
  int base = blockIdx.x * SCAN_CHUNK + tid * SCAN_ITEMS;
  int s = 0;
  #pragma unroll
  for (int j = 0; j < SCAN_ITEMS; ++j) {
    int i = base + j;
    s += (i < RN) ? hist[i] : 0;
  }
  sh[tid] = s;
  __syncthreads();
  for (int off = SCAN_BLK / 2; off > 0; off >>= 1) {
    if (tid < off) sh[tid] += sh[tid + off];
    __syncthreads();
  }
  if (tid == 0) partials[blockIdx.x] = sh[0];
}

__global__ void scanB(int* __restrict__ partials, int nblk) {
  int acc = 0;
  for (int i = 0; i < nblk; ++i) {
    int v = partials[i];
    partials[i] = acc;
    acc += v;
  }
}

__global__ void scanC(const int* __restrict__ hist, const int* __restrict__ partials,
                      int* __restrict__ starts, int RN) {
  __shared__ int sh[SCAN_BLK];
  const int tid = threadIdx.x;
  int base = blockIdx.x * SCAN_CHUNK + tid * SCAN_ITEMS;
  int loc[SCAN_ITEMS];
  int s = 0;
  #pragma unroll
  for (int j = 0; j < SCAN_ITEMS; ++j) {
    int i = base + j;
    int v = (i < RN) ? hist[i] : 0;
    loc[j] = s;
    s += v;
  }
  sh[tid] = s;
  __syncthreads();
  for (int off = 1; off < SCAN_BLK; off <<= 1) {
    int v = (tid >= off) ? sh[tid - off] : 0;
    __syncthreads();
    sh[tid] += v;
    __syncthreads();
  }
  int texcl = (tid ? sh[tid - 1] : 0) + partials[blockIdx.x];
  #pragma unroll
  for (int j = 0; j < SCAN_ITEMS; ++j) {
    int i = base + j;
    if (i < RN) starts[i] = texcl + loc[j];
  }
}

__global__ void scatter_fill(const int* __restrict__ src, const int* __restrict__ tgt,
                             const int* __restrict__ et, int* __restrict__ starts,
                             int* __restrict__ sortedsrc, int E, int N) {
  int i = blockIdx.x * blockDim.x + threadIdx.x;
  int stride = gridDim.x * blockDim.x;
  for (; i < E; i += stride) {
    int key = et[i] * N + tgt[i];
    int pos = atomicAdd(&starts[key], 1);
    sortedsrc[pos] = src[i];
  }
}

// ---------------- converts ----------------
__global__ void f32_to_bf16(const float* __restrict__ in, short* __restrict__ out, int n8) {
  int i = blockIdx.x * blockDim.x + threadIdx.x;
  int stride = gridDim.x * blockDim.x;
  for (; i < n8; i += stride) {
    const float* p = in + (size_t)i * 8;
    float4 a = *(const float4*)p;
    float4 b = *(const float4*)(p + 4);
    bf16x8 o;
    o[0] = f2bf(a.x); o[1] = f2bf(a.y); o[2] = f2bf(a.z); o[3] = f2bf(a.w);
    o[4] = f2bf(b.x); o[5] = f2bf(b.y); o[6] = f2bf(b.z); o[7] = f2bf(b.w);
    *(bf16x8*)(out + (size_t)i * 8) = o;
  }
}

// WtT[p][o][k] = (p<8 ? W[p][k][o] : root[k][o]) as bf16.  i = ((p*DOUT)+o)*128+k
__global__ void w_conv(const float* __restrict__ W, const float* __restrict__ root,
                       short* __restrict__ WtT, int dout) {
  int total = 9 * dout * 128;
  int i = blockIdx.x * blockDim.x + threadIdx.x;
  int stride = gridDim.x * blockDim.x;
  for (; i < total; i += stride) {
    int p = i / (dout * 128);
    int rem = i - p * dout * 128;
    int o = rem >> 7;          // /128
    int k = rem & 127;
    float v = (p < 8) ? W[((size_t)p * 128 + k) * dout + o]
                      : root[(size_t)k * dout + o];
    WtT[i] = f2bf(v);
  }
}

// ---------------- bf16 mean-gather: one 16-lane group per node ----------------
__global__ void gather_agg_bf16(const short* __restrict__ Xb, const int* __restrict__ sortedsrc,
                                const int* __restrict__ starts, const int* __restrict__ hist,
                                int rel, int N, short* __restrict__ aggb) {
  int n = blockIdx.x * 16 + (threadIdx.x >> 4);
  if (n >= N) return;
  const int lane = threadIdx.x & 15;
  const int key = rel * N + n;
  const int end = starts[key];
  const int cnt = hist[key];
  float acc[8] = {0.f, 0.f, 0.f, 0.f, 0.f, 0.f, 0.f, 0.f};
  for (int e = end - cnt; e < end; ++e) {
    int s = sortedsrc[e];  // uniform across group
    bf16x8 v = *(const bf16x8*)(Xb + (size_t)s * DIN + lane * 8);
    #pragma unroll
    for (int j = 0; j < 8; ++j) acc[j] += bf2f(v[j]);
  }
  float scale = 1.0f / fmaxf((float)cnt, 1.0f);
  bf16x8 o;
  #pragma unroll
  for (int j = 0; j < 8; ++j) o[j] = f2bf(acc[j] * scale);
  *(bf16x8*)(aggb + (size_t)n * DIN + lane * 8) = o;
}

// ---------------- bf16 MFMA GEMM: out[nrows,DOUT] (+)= A[nrows,128] * W ----------------
// A: bf16 [nrows][128].  WtT: bf16 [DOUT][128] (row o holds W[:,o], k-contiguous).
// INIT: out = bias + A*W.  else: out += A*W (fp32 RMW).  RELU on final pass.
// Tile: 128 rows x DOUT. 4 waves: DOUT=128 -> 2x2 grid of 64x64; DOUT=64 -> 4x1 of 32x64.
// mfma_f32_16x16x32_bf16; C/D: col=lane&15, row=(lane>>4)*4+reg (m89-verified).
template <int DOUT, bool INIT, bool RELU>
__launch_bounds__(256)
__global__ void gemm_mfma(const short* __restrict__ Abf, const short* __restrict__ WtT,
                          const float* __restrict__ bias,
                          float* __restrict__ out, int nrows) {
  constexpr int STR = 136;  // padded LDS row stride (bf16 units); 272 B, mult of 16
  __shared__ __align__(16) short As[128 * STR];
  __shared__ __align__(16) short Ws[DOUT * STR];
  const int tid = threadIdx.x;
  const int row0 = blockIdx.x * 128;

  // stage W (DOUT*128 bf16): each iter 256 thr x 8 bf16 = 16 rows
  #pragma unroll
  for (int it = 0; it < (DOUT * 128) / 2048; ++it) {
    int g = it * 2048 + tid * 8;
    int row = g >> 7, col = g & 127;
    *(bf16x8*)&Ws[row * STR + col] = *(const bf16x8*)(WtT + g);
  }
  // stage A (128 rows), zero-pad rows >= nrows
  #pragma unroll
  for (int it = 0; it < 8; ++it) {
    int g = it * 2048 + tid * 8;
    int row = g >> 7, col = g & 127;
    bf16x8 v = {0, 0, 0, 0, 0, 0, 0, 0};
    if (row0 + row < nrows) v = *(const bf16x8*)(Abf + (size_t)(row0 + row) * DIN + col);
    *(bf16x8*)&As[row * STR + col] = v;
  }
  __syncthreads();

  constexpr int WR = (DOUT == 128) ? 4 : 2;  // 16-row subtiles per wave
  constexpr int WC = 4;                      // 16-col subtiles per wave
  const int wid = tid >> 6;
  const int lane = tid & 63;
  const int wrow0 = (DOUT == 128) ? (wid >> 1) * 64 : wid * 32;
  const int wcol0 = (DOUT == 128) ? (wid & 1) * 64 : 0;
  const int lr = lane & 15;
  const int kg = (lane >> 4) * 8;

  f32x4 acc[WR][WC];
  #pragma unroll
  for (int mi = 0; mi < WR; ++mi)
    #pragma unroll
    for (int ni = 0; ni < WC; ++ni)
      acc[mi][ni] = (f32x4){0.f, 0.f, 0.f, 0.f};

  #pragma unroll
  for (int kk = 0; kk < 4; ++kk) {
    const int k0 = kk * 32 + kg;
    bf16x8 a[WR], b[WC];
    #pragma unroll
    for (int mi = 0; mi < WR; ++mi)
      a[mi] = *(const bf16x8*)&As[(wrow0 + mi * 16 + lr) * STR + k0];
    #pragma unroll
    for (int ni = 0; ni < WC; ++ni)
      b[ni] = *(const bf16x8*)&Ws[(wcol0 + ni * 16 + lr) * STR + k0];
    #pragma unroll
    for (int mi = 0; mi < WR; ++mi)
      #pragma unroll
      for (int ni = 0; ni < WC; ++ni)
        acc[mi][ni] = __builtin_amdgcn_mfma_f32_16x16x32_bf16(a[mi], b[ni], acc[mi][ni], 0, 0, 0);
  }

  // epilogue: D row = (lane>>4)*4 + r, col = lane&15 within each 16x16 subtile
  const int rbase = (lane >> 4) * 4;
  #pragma unroll
  for (int mi = 0; mi < WR; ++mi) {
    #pragma unroll
    for (int ni = 0; ni < WC; ++ni) {
      const int col = wcol0 + ni * 16 + lr;
      #pragma unroll
      for (int r = 0; r < 4; ++r) {
        int rr = row0 + wrow0 + mi * 16 + rbase + r;
        if (rr >= nrows) continue;
        float* p = out + (size_t)rr * DOUT + col;
        float v = acc[mi][ni][r];
        if (INIT) v += bias[col];
        else      v += *p;
        if (RELU) v = fmaxf(v, 0.f);
        *p = v;
      }
    }
  }
}

// ---------------- host ----------------
extern "C" void kernel_launch(void* const* d_in, const int* in_sizes, int n_in,
                              void* d_out, int out_size, void* d_ws, size_t ws_size,
                              hipStream_t stream) {
  const float* x     = (const float*)d_in[0];
  const int*   ei    = (const int*)d_in[1];
  const int*   et    = (const int*)d_in[2];
  const float* W1    = (const float*)d_in[3];
  const float* root1 = (const float*)d_in[4];
  const float* b1    = (const float*)d_in[5];
  const float* W2    = (const float*)d_in[6];
  const float* root2 = (const float*)d_in[7];
  const float* b2    = (const float*)d_in[8];
  float* out = (float*)d_out;

  const int N = in_sizes[0] / DIN;
  const int E = in_sizes[1] / 2;
  const int* src = ei;
  const int* tgt = ei + E;
  const int RN = N * NREL;

  // ws layout (256B-aligned chunks):
  // hist[RN] | starts[RN] | partials | sortedsrc[E] | xb(=hb)[N*128]bf16 |
  // aggb[N*128]bf16 | h[N*128]f32 | WtT1[9*128*128]bf16 | WtT2[9*64*128]bf16  ~116MB
  char* ws = (char*)d_ws;
  size_t off = 0;
  auto take = [&](size_t bytes) { char* p = ws + off; off += (bytes + 255) & ~(size_t)255; return p; };
  int*   hist      = (int*)take((size_t)RN * 4);
  int*   starts    = (int*)take((size_t)RN * 4);
  int*   partials  = (int*)take(1024);
  int*   sortedsrc = (int*)take((size_t)E * 4);
  short* xb        = (short*)take((size_t)N * DIN * 2);  // layer2: hb aliases xb
  short* aggb      = (short*)take((size_t)N * DIN * 2);
  float* h         = (float*)take((size_t)N * DIN * 4);
  short* WtT1      = (short*)take((size_t)9 * 128 * 128 * 2);
  short* WtT2      = (short*)take((size_t)9 * 64 * 128 * 2);
  short* hb        = xb;

  const int gb = (N + 127) / 128;   // GEMM blocks (128-row tiles)
  const int ga = (N + 15) / 16;     // gather blocks (16 nodes/block)
  const int nblkA = (RN + SCAN_CHUNK - 1) / SCAN_CHUNK;

  // ---- CSR build (once; graph shared by both layers) ----
  zero_ints<<<(RN / 4 + 255) / 256, 256, 0, stream>>>((int4*)hist, RN / 4);
  hist_kernel<<<2048, 256, 0, stream>>>(tgt, et, hist, E, N);
  scanA<<<nblkA, SCAN_BLK, 0, stream>>>(hist, partials, RN);
  scanB<<<1, 1, 0, stream>>>(partials, nblkA);
  scanC<<<nblkA, SCAN_BLK, 0, stream>>>(hist, partials, starts, RN);
  scatter_fill<<<2048, 256, 0, stream>>>(src, tgt, et, starts, sortedsrc, E, N);

  // ---- weight convert+transpose, x -> bf16 ----
  w_conv<<<576, 256, 0, stream>>>(W1, root1, WtT1, 128);
  w_conv<<<288, 256, 0, stream>>>(W2, root2, WtT2, 64);
  f32_to_bf16<<<2048, 256, 0, stream>>>(x, xb, N * DIN / 8);

  // ---- layer 1: h = relu(x@root1 + b1 + sum_r mean_r @ W1_r) ----
  gemm_mfma<128, true, false><<<gb, 256, 0, stream>>>(xb, WtT1 + (size_t)8 * 128 * 128, b1, h, N);
  for (int r = 0; r < NREL; ++r) {
    gather_agg_bf16<<<ga, 256, 0, stream>>>(xb, sortedsrc, starts, hist, r, N, aggb);
    const short* Wr = WtT1 + (size_t)r * 128 * 128;
    if (r < 7)
      gemm_mfma<128, false, false><<<gb, 256, 0, stream>>>(aggb, Wr, nullptr, h, N);
    else
      gemm_mfma<128, false, true><<<gb, 256, 0, stream>>>(aggb, Wr, nullptr, h, N);
  }

  // ---- h -> bf16 (hb aliases xb; all xb readers are done) ----
  f32_to_bf16<<<2048, 256, 0, stream>>>(h, hb, N * DIN / 8);

  // ---- layer 2: out = h@root2 + b2 + sum_r mean_r @ W2_r ----
  gemm_mfma<64, true, false><<<gb, 256, 0, stream>>>(hb, WtT2 + (size_t)8 * 64 * 128, b2, out, N);
  for (int r = 0; r < NREL; ++r) {
    gather_agg_bf16<<<ga, 256, 0, stream>>>(hb, sortedsrc, starts, hist, r, N, aggb);
    const short* Wr = WtT2 + (size_t)r * 64 * 128;
    gemm_mfma<64, false, false><<<gb, 256, 0, stream>>>(aggb, Wr, nullptr, out, N);
  }
}

// Round 8
// 1014.515 us; speedup vs baseline: 6.8988x; 1.2486x over previous
//
#include <hip/hip_runtime.h>
#include <cstdint>
#include <cstddef>

// RGCN 2-layer forward, round 8: per-layer FULL FUSION.
// r7 evidence: 1267us total; scatter_fill 123us; rest = intermediate traffic
// (aggb 410MB, f32 h RMW ~1.8GB across 17 GEMM dispatches). Fix: one kernel per
// layer; 9 panels (8 rels + root) looped in-kernel; gather-mean -> LDS A-tile ->
// MFMA accumulate in REGISTERS; bias/relu in epilogue; layer-1 writes bf16 hb
// directly. aggb + h f32 + 33 dispatches eliminated. B-frags from L2 (no W LDS)
// -> LDS 34.8KB -> 4 blocks/CU. MFMA layout HW-validated in r7 (absmax 0.03125).

#define DIN 128
#define NREL 8
#define SCAN_BLK 256
#define SCAN_ITEMS 16
#define SCAN_CHUNK (SCAN_BLK * SCAN_ITEMS)

typedef short bf16x8 __attribute__((ext_vector_type(8)));
typedef float f32x4 __attribute__((ext_vector_type(4)));

__device__ inline float bf2f(short s) {
  return __uint_as_float(((unsigned int)(unsigned short)s) << 16);
}
__device__ inline short f2bf(float f) {  // RTNE
  unsigned int u = __float_as_uint(f);
  unsigned int r = (u + 0x7FFFu + ((u >> 16) & 1u)) >> 16;
  return (short)r;
}

// ---------------- CSR build (validated r7) ----------------
__global__ void zero_ints(int4* __restrict__ p, int n4) {
  int i = blockIdx.x * blockDim.x + threadIdx.x;
  int stride = gridDim.x * blockDim.x;
  int4 z; z.x = z.y = z.z = z.w = 0;
  for (; i < n4; i += stride) p[i] = z;
}

__global__ void hist_kernel(const int* __restrict__ tgt, const int* __restrict__ et,
                            int* __restrict__ hist, int E, int N) {
  int i = blockIdx.x * blockDim.x + threadIdx.x;
  int stride = gridDim.x * blockDim.x;
  for (; i < E; i += stride)
    atomicAdd(&hist[et[i] * N + tgt[i]], 1);
}

__global__ void scanA(const int* __restrict__ hist, int* __restrict__ partials, int RN) {
  __shared__ int sh[SCAN_BLK];
  const int tid = threadIdx.x;
  int base = blockIdx.x * SCAN_CHUNK + tid * SCAN_ITEMS;
  int s = 0;
  #pragma unroll
  for (int j = 0; j < SCAN_ITEMS; ++j) {
    int i = base + j;
    s += (i < RN) ? hist[i] : 0;
  }
  sh[tid] = s;
  __syncthreads();
  for (int off = SCAN_BLK / 2; off > 0; off >>= 1) {
    if (tid < off) sh[tid] += sh[tid + off];
    __syncthreads();
  }
  if (tid == 0) partials[blockIdx.x] = sh[0];
}

__global__ void scanB(int* __restrict__ partials, int nblk) {
  int acc = 0;
  for (int i = 0; i < nblk; ++i) {
    int v = partials[i];
    partials[i] = acc;
    acc += v;
  }
}

__global__ void scanC(const int* __restrict__ hist, const int* __restrict__ partials,
                      int* __restrict__ starts, int RN) {
  __shared__ int sh[SCAN_BLK];
  const int tid = threadIdx.x;
  int base = blockIdx.x * SCAN_CHUNK + tid * SCAN_ITEMS;
  int loc[SCAN_ITEMS];
  int s = 0;
  #pragma unroll
  for (int j = 0; j < SCAN_ITEMS; ++j) {
    int i = base + j;
    int v = (i < RN) ? hist[i] : 0;
    loc[j] = s;
    s += v;
  }
  sh[tid] = s;
  __syncthreads();
  for (int off = 1; off < SCAN_BLK; off <<= 1) {
    int v = (tid >= off) ? sh[tid - off] : 0;
    __syncthreads();
    sh[tid] += v;
    __syncthreads();
  }
  int texcl = (tid ? sh[tid - 1] : 0) + partials[blockIdx.x];
  #pragma unroll
  for (int j = 0; j < SCAN_ITEMS; ++j) {
    int i = base + j;
    if (i < RN) starts[i] = texcl + loc[j];
  }
}

__global__ void scatter_fill(const int* __restrict__ src, const int* __restrict__ tgt,
                             const int* __restrict__ et, int* __restrict__ starts,
                             int* __restrict__ sortedsrc, int E, int N) {
  int i = blockIdx.x * blockDim.x + threadIdx.x;
  int stride = gridDim.x * blockDim.x;
  for (; i < E; i += stride) {
    int key = et[i] * N + tgt[i];
    int pos = atomicAdd(&starts[key], 1);
    sortedsrc[pos] = src[i];
  }
}

// ---------------- converts (validated r7) ----------------
__global__ void f32_to_bf16(const float* __restrict__ in, short* __restrict__ out, int n8) {
  int i = blockIdx.x * blockDim.x + threadIdx.x;
  int stride = gridDim.x * blockDim.x;
  for (; i < n8; i += stride) {
    const float* p = in + (size_t)i * 8;
    float4 a = *(const float4*)p;
    float4 b = *(const float4*)(p + 4);
    bf16x8 o;
    o[0] = f2bf(a.x); o[1] = f2bf(a.y); o[2] = f2bf(a.z); o[3] = f2bf(a.w);
    o[4] = f2bf(b.x); o[5] = f2bf(b.y); o[6] = f2bf(b.z); o[7] = f2bf(b.w);
    *(bf16x8*)(out + (size_t)i * 8) = o;
  }
}

// WtT[p][o][k] = (p<8 ? W[p][k][o] : root[k][o]) as bf16.  i = ((p*DOUT)+o)*128+k
__global__ void w_conv(const float* __restrict__ W, const float* __restrict__ root,
                       short* __restrict__ WtT, int dout) {
  int total = 9 * dout * 128;
  int i = blockIdx.x * blockDim.x + threadIdx.x;
  int stride = gridDim.x * blockDim.x;
  for (; i < total; i += stride) {
    int p = i / (dout * 128);
    int rem = i - p * dout * 128;
    int o = rem >> 7;
    int k = rem & 127;
    float v = (p < 8) ? W[((size_t)p * 128 + k) * dout + o]
                      : root[(size_t)k * dout + o];
    WtT[i] = f2bf(v);
  }
}

// ---------------- fused RGCN layer ----------------
// One 128-node tile per block, 256 threads (4 waves). Loop 9 panels:
//   p<8 : gather-mean rel-p segments into LDS A-tile (16-lane group per node row)
//   p==8: root panel, A-tile = Xb rows (vector copy)
// then MFMA-accumulate A * WtT[p] into register acc. Epilogue: +bias, optional
// relu, write bf16 (layer 1) or f32 (layer 2). B-frags read from L2 (WtT is
// 294KB, resident); no W staging keeps LDS at 34.8KB -> 4 blocks/CU.
// MFMA C/D: col=lane&15, row=(lane>>4)*4+reg (HW-validated r7).
template <int DOUT, bool OUT_BF16_RELU>
__launch_bounds__(256)
__global__ void rgcn_layer(const short* __restrict__ Xb, const short* __restrict__ WtT,
                           const int* __restrict__ sortedsrc, const int* __restrict__ starts,
                           const int* __restrict__ hist, const float* __restrict__ bias,
                           void* __restrict__ outv, int N) {
  constexpr int STR = 136;  // LDS row stride (bf16): 272B, mult of 16
  __shared__ __align__(16) short As[128 * STR];
  const int tid = threadIdx.x;
  const int row0 = blockIdx.x * 128;
  const int wid = tid >> 6, lane = tid & 63;
  constexpr int WR = (DOUT == 128) ? 4 : 2;
  constexpr int WC = 4;
  const int wrow0 = (DOUT == 128) ? (wid >> 1) * 64 : wid * 32;
  const int wcol0 = (DOUT == 128) ? (wid & 1) * 64 : 0;
  const int lr = lane & 15;
  const int kg = (lane >> 4) * 8;
  const int g16 = tid >> 4;  // gather group 0..15
  const int l16 = tid & 15;  // lane in group -> owns cols l16*8..+7

  f32x4 acc[WR][WC];
  #pragma unroll
  for (int mi = 0; mi < WR; ++mi)
    #pragma unroll
    for (int ni = 0; ni < WC; ++ni)
      acc[mi][ni] = (f32x4){0.f, 0.f, 0.f, 0.f};

  for (int p = 0; p < 9; ++p) {
    // ---- build A tile ----
    if (p == 8) {
      #pragma unroll
      for (int it = 0; it < 8; ++it) {
        int g = it * 2048 + tid * 8;
        int row = g >> 7, col = g & 127;
        bf16x8 v = {0, 0, 0, 0, 0, 0, 0, 0};
        if (row0 + row < N) v = *(const bf16x8*)(Xb + (size_t)(row0 + row) * DIN + col);
        *(bf16x8*)&As[row * STR + col] = v;
      }
    } else {
      #pragma unroll
      for (int it = 0; it < 8; ++it) {
        int row = it * 16 + g16;
        int n = row0 + row;
        float a[8] = {0.f, 0.f, 0.f, 0.f, 0.f, 0.f, 0.f, 0.f};
        if (n < N) {
          int key = p * N + n;
          int end = starts[key];
          int cnt = hist[key];
          for (int e = end - cnt; e < end; ++e) {
            int s = sortedsrc[e];  // uniform across group
            bf16x8 v = *(const bf16x8*)(Xb + (size_t)s * DIN + l16 * 8);
            #pragma unroll
            for (int j = 0; j < 8; ++j) a[j] += bf2f(v[j]);
          }
          float sc = 1.0f / fmaxf((float)cnt, 1.0f);
          #pragma unroll
          for (int j = 0; j < 8; ++j) a[j] *= sc;
        }
        bf16x8 o;
        #pragma unroll
        for (int j = 0; j < 8; ++j) o[j] = f2bf(a[j]);
        *(bf16x8*)&As[row * STR + l16 * 8] = o;
      }
    }
    __syncthreads();

    // ---- MFMA accumulate: A from LDS, B from global (L2-resident WtT) ----
    const short* Wp = WtT + (size_t)p * DOUT * 128;
    #pragma unroll
    for (int kk = 0; kk < 4; ++kk) {
      const int k0 = kk * 32 + kg;
      bf16x8 a[WR], b[WC];
      #pragma unroll
      for (int mi = 0; mi < WR; ++mi)
        a[mi] = *(const bf16x8*)&As[(wrow0 + mi * 16 + lr) * STR + k0];
      #pragma unroll
      for (int ni = 0; ni < WC; ++ni)
        b[ni] = *(const bf16x8*)(Wp + (size_t)(wcol0 + ni * 16 + lr) * 128 + k0);
      #pragma unroll
      for (int mi = 0; mi < WR; ++mi)
        #pragma unroll
        for (int ni = 0; ni < WC; ++ni)
          acc[mi][ni] = __builtin_amdgcn_mfma_f32_16x16x32_bf16(a[mi], b[ni], acc[mi][ni], 0, 0, 0);
    }
    __syncthreads();  // As reused next panel
  }

  // ---- epilogue: +bias, relu (layer1), store ----
  const int rbase = (lane >> 4) * 4;
  #pragma unroll
  for (int mi = 0; mi < WR; ++mi) {
    #pragma unroll
    for (int ni = 0; ni < WC; ++ni) {
      const int col = wcol0 + ni * 16 + lr;
      const float bcol = bias[col];
      #pragma unroll
      for (int r = 0; r < 4; ++r) {
        int rr = row0 + wrow0 + mi * 16 + rbase + r;
        if (rr >= N) continue;
        float v = acc[mi][ni][r] + bcol;
        if (OUT_BF16_RELU) {
          v = fmaxf(v, 0.f);
          ((short*)outv)[(size_t)rr * DOUT + col] = f2bf(v);
        } else {
          ((float*)outv)[(size_t)rr * DOUT + col] = v;
        }
      }
    }
  }
}

// ---------------- host ----------------
extern "C" void kernel_launch(void* const* d_in, const int* in_sizes, int n_in,
                              void* d_out, int out_size, void* d_ws, size_t ws_size,
                              hipStream_t stream) {
  const float* x     = (const float*)d_in[0];
  const int*   ei    = (const int*)d_in[1];
  const int*   et    = (const int*)d_in[2];
  const float* W1    = (const float*)d_in[3];
  const float* root1 = (const float*)d_in[4];
  const float* b1    = (const float*)d_in[5];
  const float* W2    = (const float*)d_in[6];
  const float* root2 = (const float*)d_in[7];
  const float* b2    = (const float*)d_in[8];
  float* out = (float*)d_out;

  const int N = in_sizes[0] / DIN;
  const int E = in_sizes[1] / 2;
  const int* src = ei;
  const int* tgt = ei + E;
  const int RN = N * NREL;

  // ws: hist | starts | partials | sortedsrc | xb | hb | WtT1 | WtT2  (~65 MB)
  char* ws = (char*)d_ws;
  size_t off = 0;
  auto take = [&](size_t bytes) { char* p = ws + off; off += (bytes + 255) & ~(size_t)255; return p; };
  int*   hist      = (int*)take((size_t)RN * 4);
  int*   starts    = (int*)take((size_t)RN * 4);
  int*   partials  = (int*)take(1024);
  int*   sortedsrc = (int*)take((size_t)E * 4);
  short* xb        = (short*)take((size_t)N * DIN * 2);
  short* hb        = (short*)take((size_t)N * DIN * 2);
  short* WtT1      = (short*)take((size_t)9 * 128 * 128 * 2);
  short* WtT2      = (short*)take((size_t)9 * 64 * 128 * 2);

  const int gb = (N + 127) / 128;
  const int nblkA = (RN + SCAN_CHUNK - 1) / SCAN_CHUNK;

  // ---- CSR build (once; graph shared by both layers) ----
  zero_ints<<<(RN / 4 + 255) / 256, 256, 0, stream>>>((int4*)hist, RN / 4);
  hist_kernel<<<2048, 256, 0, stream>>>(tgt, et, hist, E, N);
  scanA<<<nblkA, SCAN_BLK, 0, stream>>>(hist, partials, RN);
  scanB<<<1, 1, 0, stream>>>(partials, nblkA);
  scanC<<<nblkA, SCAN_BLK, 0, stream>>>(hist, partials, starts, RN);
  scatter_fill<<<2048, 256, 0, stream>>>(src, tgt, et, starts, sortedsrc, E, N);

  // ---- weight convert+transpose, x -> bf16 ----
  w_conv<<<576, 256, 0, stream>>>(W1, root1, WtT1, 128);
  w_conv<<<288, 256, 0, stream>>>(W2, root2, WtT2, 64);
  f32_to_bf16<<<2048, 256, 0, stream>>>(x, xb, N * DIN / 8);

  // ---- fused layers ----
  rgcn_layer<128, true><<<gb, 256, 0, stream>>>(
      xb, WtT1, sortedsrc, starts, hist, b1, hb, N);
  rgcn_layer<64, false><<<gb, 256, 0, stream>>>(
      hb, WtT2, sortedsrc, starts, hist, b2, out, N);
}

// Round 9
// 885.155 us; speedup vs baseline: 7.9070x; 1.1461x over previous
//
#include <hip/hip_runtime.h>
#include <cstdint>
#include <cstddef>

// RGCN 2-layer forward, round 9: barrier-free fused layer (register gather).
// r8 evidence: fused layer latency-bound (MfmaUtil 2.6%, VALUBusy 11%, Occ 16.5%)
// -- 18 barriers/block serialize gather and MFMA phases; 782 blocks ~3/CU.
// Fix: no LDS, no __syncthreads. Each wave owns 16 rows x full DOUT; the 4 lanes
// sharing (lane&15) walk that row's (rel,row) segment together, each accumulating
// its own 8-wide k-slice of the mean in f32 regs (exactly the MFMA A-frag slice:
// A[row=lane&15][k=(lane>>4)*8+j]). Convert to bf16 frags, MFMA-accumulate over
// 9 panels (8 rels + root), epilogue bias/relu. 1563 blocks, launch_bounds(256,4).
// Numeric path identical to r8 (absmax 0.03125 expected unchanged).

#define DIN 128
#define NREL 8
#define SCAN_BLK 256
#define SCAN_ITEMS 16
#define SCAN_CHUNK (SCAN_BLK * SCAN_ITEMS)

typedef short bf16x8 __attribute__((ext_vector_type(8)));
typedef float f32x4 __attribute__((ext_vector_type(4)));

__device__ inline float bf2f(short s) {
  return __uint_as_float(((unsigned int)(unsigned short)s) << 16);
}
__device__ inline short f2bf(float f) {  // RTNE
  unsigned int u = __float_as_uint(f);
  unsigned int r = (u + 0x7FFFu + ((u >> 16) & 1u)) >> 16;
  return (short)r;
}

// ---------------- CSR build (validated r7/r8) ----------------
__global__ void zero_ints(int4* __restrict__ p, int n4) {
  int i = blockIdx.x * blockDim.x + threadIdx.x;
  int stride = gridDim.x * blockDim.x;
  int4 z; z.x = z.y = z.z = z.w = 0;
  for (; i < n4; i += stride) p[i] = z;
}

__global__ void hist_kernel(const int* __restrict__ tgt, const int* __restrict__ et,
                            int* __restrict__ hist, int E, int N) {
  int i = blockIdx.x * blockDim.x + threadIdx.x;
  int stride = gridDim.x * blockDim.x;
  for (; i < E; i += stride)
    atomicAdd(&hist[et[i] * N + tgt[i]], 1);
}

__global__ void scanA(const int* __restrict__ hist, int* __restrict__ partials, int RN) {
  __shared__ int sh[SCAN_BLK];
  const int tid = threadIdx.x;
  int base = blockIdx.x * SCAN_CHUNK + tid * SCAN_ITEMS;
  int s = 0;
  #pragma unroll
  for (int j = 0; j < SCAN_ITEMS; ++j) {
    int i = base + j;
    s += (i < RN) ? hist[i] : 0;
  }
  sh[tid] = s;
  __syncthreads();
  for (int off = SCAN_BLK / 2; off > 0; off >>= 1) {
    if (tid < off) sh[tid] += sh[tid + off];
    __syncthreads();
  }
  if (tid == 0) partials[blockIdx.x] = sh[0];
}

__global__ void scanB(int* __restrict__ partials, int nblk) {
  int acc = 0;
  for (int i = 0; i < nblk; ++i) {
    int v = partials[i];
    partials[i] = acc;
    acc += v;
  }
}

__global__ void scanC(const int* __restrict__ hist, const int* __restrict__ partials,
                      int* __restrict__ starts, int RN) {
  __shared__ int sh[SCAN_BLK];
  const int tid = threadIdx.x;
  int base = blockIdx.x * SCAN_CHUNK + tid * SCAN_ITEMS;
  int loc[SCAN_ITEMS];
  int s = 0;
  #pragma unroll
  for (int j = 0; j < SCAN_ITEMS; ++j) {
    int i = base + j;
    int v = (i < RN) ? hist[i] : 0;
    loc[j] = s;
    s += v;
  }
  sh[tid] = s;
  __syncthreads();
  for (int off = 1; off < SCAN_BLK; off <<= 1) {
    int v = (tid >= off) ? sh[tid - off] : 0;
    __syncthreads();
    sh[tid] += v;
    __syncthreads();
  }
  int texcl = (tid ? sh[tid - 1] : 0) + partials[blockIdx.x];
  #pragma unroll
  for (int j = 0; j < SCAN_ITEMS; ++j) {
    int i = base + j;
    if (i < RN) starts[i] = texcl + loc[j];
  }
}

__global__ void scatter_fill(const int* __restrict__ src, const int* __restrict__ tgt,
                             const int* __restrict__ et, int* __restrict__ starts,
                             int* __restrict__ sortedsrc, int E, int N) {
  int i = blockIdx.x * blockDim.x + threadIdx.x;
  int stride = gridDim.x * blockDim.x;
  for (; i < E; i += stride) {
    int key = et[i] * N + tgt[i];
    int pos = atomicAdd(&starts[key], 1);
    sortedsrc[pos] = src[i];
  }
}

// ---------------- converts (validated r7/r8) ----------------
__global__ void f32_to_bf16(const float* __restrict__ in, short* __restrict__ out, int n8) {
  int i = blockIdx.x * blockDim.x + threadIdx.x;
  int stride = gridDim.x * blockDim.x;
  for (; i < n8; i += stride) {
    const float* p = in + (size_t)i * 8;
    float4 a = *(const float4*)p;
    float4 b = *(const float4*)(p + 4);
    bf16x8 o;
    o[0] = f2bf(a.x); o[1] = f2bf(a.y); o[2] = f2bf(a.z); o[3] = f2bf(a.w);
    o[4] = f2bf(b.x); o[5] = f2bf(b.y); o[6] = f2bf(b.z); o[7] = f2bf(b.w);
    *(bf16x8*)(out + (size_t)i * 8) = o;
  }
}

// WtT[p][o][k] = (p<8 ? W[p][k][o] : root[k][o]) as bf16.
__global__ void w_conv(const float* __restrict__ W, const float* __restrict__ root,
                       short* __restrict__ WtT, int dout) {
  int total = 9 * dout * 128;
  int i = blockIdx.x * blockDim.x + threadIdx.x;
  int stride = gridDim.x * blockDim.x;
  for (; i < total; i += stride) {
    int p = i / (dout * 128);
    int rem = i - p * dout * 128;
    int o = rem >> 7;
    int k = rem & 127;
    float v = (p < 8) ? W[((size_t)p * 128 + k) * dout + o]
                      : root[(size_t)k * dout + o];
    WtT[i] = f2bf(v);
  }
}

// ---------------- barrier-free fused RGCN layer ----------------
// 256 threads = 4 independent waves; wave owns rows [blk*64 + wid*16, +16) x DOUT.
// Lane (lr = lane&15, kg = (lane>>4)*8) gathers row (base+lr)'s per-rel mean at
// k-slices kk*32+kg directly into f32 regs == its MFMA A-frag slice. 9 panels
// accumulated in registers; no LDS, no barriers.
template <int DOUT, bool OUT_BF16_RELU>
__launch_bounds__(256, 4)
__global__ void rgcn_layer(const short* __restrict__ Xb, const short* __restrict__ WtT,
                           const int* __restrict__ sortedsrc, const int* __restrict__ starts,
                           const int* __restrict__ hist, const float* __restrict__ bias,
                           void* __restrict__ outv, int N) {
  constexpr int WC = DOUT / 16;
  const int tid = threadIdx.x;
  const int wid = tid >> 6;
  const int lane = tid & 63;
  const int lr = lane & 15;
  const int kg = (lane >> 4) * 8;
  const int row = blockIdx.x * 64 + wid * 16 + lr;  // A-row this lane serves
  const bool rowok = row < N;

  f32x4 acc[WC];
  #pragma unroll
  for (int ni = 0; ni < WC; ++ni) acc[ni] = (f32x4){0.f, 0.f, 0.f, 0.f};

  #pragma unroll 1
  for (int p = 0; p < 9; ++p) {
    bf16x8 af[4];
    if (p == 8) {
      // root panel: A = Xb row directly
      #pragma unroll
      for (int kk = 0; kk < 4; ++kk) {
        bf16x8 v = {0, 0, 0, 0, 0, 0, 0, 0};
        if (rowok) v = *(const bf16x8*)(Xb + (size_t)row * DIN + kk * 32 + kg);
        af[kk] = v;
      }
    } else {
      float ga[4][8];
      #pragma unroll
      for (int kk = 0; kk < 4; ++kk)
        #pragma unroll
        for (int j = 0; j < 8; ++j) ga[kk][j] = 0.f;
      if (rowok) {
        const int key = p * N + row;
        const int end = starts[key];
        const int cnt = hist[key];
        for (int e = end - cnt; e < end; ++e) {
          int s = sortedsrc[e];
          const short* xp = Xb + (size_t)s * DIN + kg;
          #pragma unroll
          for (int kk = 0; kk < 4; ++kk) {
            bf16x8 v = *(const bf16x8*)(xp + kk * 32);
            #pragma unroll
            for (int j = 0; j < 8; ++j) ga[kk][j] += bf2f(v[j]);
          }
        }
        const float sc = 1.0f / fmaxf((float)cnt, 1.0f);
        #pragma unroll
        for (int kk = 0; kk < 4; ++kk)
          #pragma unroll
          for (int j = 0; j < 8; ++j) ga[kk][j] *= sc;
      }
      #pragma unroll
      for (int kk = 0; kk < 4; ++kk) {
        bf16x8 o;
        #pragma unroll
        for (int j = 0; j < 8; ++j) o[j] = f2bf(ga[kk][j]);
        af[kk] = o;
      }
    }
    // MFMA accumulate: B frags straight from L2-resident WtT
    const short* Wp = WtT + (size_t)p * DOUT * 128;
    #pragma unroll
    for (int kk = 0; kk < 4; ++kk) {
      #pragma unroll
      for (int ni = 0; ni < WC; ++ni) {
        bf16x8 b = *(const bf16x8*)(Wp + (size_t)(ni * 16 + lr) * 128 + kk * 32 + kg);
        acc[ni] = __builtin_amdgcn_mfma_f32_16x16x32_bf16(af[kk], b, acc[ni], 0, 0, 0);
      }
    }
  }

  // epilogue: +bias, relu (layer1), store. D: col=lane&15, row=(lane>>4)*4+r.
  const int rbase = (lane >> 4) * 4;
  const int orow0 = blockIdx.x * 64 + wid * 16 + rbase;
  #pragma unroll
  for (int ni = 0; ni < WC; ++ni) {
    const int col = ni * 16 + lr;
    const float bcol = bias[col];
    #pragma unroll
    for (int r = 0; r < 4; ++r) {
      const int rr = orow0 + r;
      if (rr >= N) continue;
      float v = acc[ni][r] + bcol;
      if (OUT_BF16_RELU) {
        v = fmaxf(v, 0.f);
        ((short*)outv)[(size_t)rr * DOUT + col] = f2bf(v);
      } else {
        ((float*)outv)[(size_t)rr * DOUT + col] = v;
      }
    }
  }
}

// ---------------- host ----------------
extern "C" void kernel_launch(void* const* d_in, const int* in_sizes, int n_in,
                              void* d_out, int out_size, void* d_ws, size_t ws_size,
                              hipStream_t stream) {
  const float* x     = (const float*)d_in[0];
  const int*   ei    = (const int*)d_in[1];
  const int*   et    = (const int*)d_in[2];
  const float* W1    = (const float*)d_in[3];
  const float* root1 = (const float*)d_in[4];
  const float* b1    = (const float*)d_in[5];
  const float* W2    = (const float*)d_in[6];
  const float* root2 = (const float*)d_in[7];
  const float* b2    = (const float*)d_in[8];
  float* out = (float*)d_out;

  const int N = in_sizes[0] / DIN;
  const int E = in_sizes[1] / 2;
  const int* src = ei;
  const int* tgt = ei + E;
  const int RN = N * NREL;

  // ws: hist | starts | partials | sortedsrc | xb | hb | WtT1 | WtT2  (~65 MB)
  char* ws = (char*)d_ws;
  size_t off = 0;
  auto take = [&](size_t bytes) { char* p = ws + off; off += (bytes + 255) & ~(size_t)255; return p; };
  int*   hist      = (int*)take((size_t)RN * 4);
  int*   starts    = (int*)take((size_t)RN * 4);
  int*   partials  = (int*)take(1024);
  int*   sortedsrc = (int*)take((size_t)E * 4);
  short* xb        = (short*)take((size_t)N * DIN * 2);
  short* hb        = (short*)take((size_t)N * DIN * 2);
  short* WtT1      = (short*)take((size_t)9 * 128 * 128 * 2);
  short* WtT2      = (short*)take((size_t)9 * 64 * 128 * 2);

  const int gbl = (N + 63) / 64;   // layer blocks (64 rows / block, 4 waves)
  const int nblkA = (RN + SCAN_CHUNK - 1) / SCAN_CHUNK;

  // ---- CSR build (once; graph shared by both layers) ----
  zero_ints<<<(RN / 4 + 255) / 256, 256, 0, stream>>>((int4*)hist, RN / 4);
  hist_kernel<<<2048, 256, 0, stream>>>(tgt, et, hist, E, N);
  scanA<<<nblkA, SCAN_BLK, 0, stream>>>(hist, partials, RN);
  scanB<<<1, 1, 0, stream>>>(partials, nblkA);
  scanC<<<nblkA, SCAN_BLK, 0, stream>>>(hist, partials, starts, RN);
  scatter_fill<<<2048, 256, 0, stream>>>(src, tgt, et, starts, sortedsrc, E, N);

  // ---- weight convert+transpose, x -> bf16 ----
  w_conv<<<576, 256, 0, stream>>>(W1, root1, WtT1, 128);
  w_conv<<<288, 256, 0, stream>>>(W2, root2, WtT2, 64);
  f32_to_bf16<<<2048, 256, 0, stream>>>(x, xb, N * DIN / 8);

  // ---- fused layers (barrier-free) ----
  rgcn_layer<128, true><<<gbl, 256, 0, stream>>>(
      xb, WtT1, sortedsrc, starts, hist, b1, hb, N);
  rgcn_layer<64, false><<<gbl, 256, 0, stream>>>(
      hb, WtT2, sortedsrc, starts, hist, b2, out, N);
}

// Round 11
// 793.061 us; speedup vs baseline: 8.8252x; 1.1161x over previous
//
#include <hip/hip_runtime.h>
#include <cstdint>
#include <cstddef>

// RGCN 2-layer forward, round 10 resubmit (broker timeout; never ran).
// Panel-PARALLEL fused layer. r9 evidence: latency-bound (MfmaUtil 3.3%,
// VALUBusy 13.8%, Occ 32%): 8 panels serial per wave x divergent max-cnt segment
// walks x only 6252 waves. Fix: 4 waves share the block's 16 rows; wave w handles
// panels {w, w+4} (+root on wave 0), partial C in regs, LDS reduce (+bias/relu).
// 4x shorter chains, 4x more waves (25K), full occupancy. CSR build unchanged.

#define DIN 128
#define NREL 8
#define SCAN_BLK 256
#define SCAN_ITEMS 16
#define SCAN_CHUNK (SCAN_BLK * SCAN_ITEMS)

typedef short bf16x8 __attribute__((ext_vector_type(8)));
typedef float f32x4 __attribute__((ext_vector_type(4)));

__device__ inline float bf2f(short s) {
  return __uint_as_float(((unsigned int)(unsigned short)s) << 16);
}
__device__ inline short f2bf(float f) {  // RTNE
  unsigned int u = __float_as_uint(f);
  unsigned int r = (u + 0x7FFFu + ((u >> 16) & 1u)) >> 16;
  return (short)r;
}

// ---------------- CSR build (validated r7-r9) ----------------
__global__ void zero_ints(int4* __restrict__ p, int n4) {
  int i = blockIdx.x * blockDim.x + threadIdx.x;
  int stride = gridDim.x * blockDim.x;
  int4 z; z.x = z.y = z.z = z.w = 0;
  for (; i < n4; i += stride) p[i] = z;
}

__global__ void hist_kernel(const int* __restrict__ tgt, const int* __restrict__ et,
                            int* __restrict__ hist, int E, int N) {
  int i = blockIdx.x * blockDim.x + threadIdx.x;
  int stride = gridDim.x * blockDim.x;
  for (; i < E; i += stride)
    atomicAdd(&hist[et[i] * N + tgt[i]], 1);
}

__global__ void scanA(const int* __restrict__ hist, int* __restrict__ partials, int RN) {
  __shared__ int sh[SCAN_BLK];
  const int tid = threadIdx.x;
  int base = blockIdx.x * SCAN_CHUNK + tid * SCAN_ITEMS;
  int s = 0;
  #pragma unroll
  for (int j = 0; j < SCAN_ITEMS; ++j) {
    int i = base + j;
    s += (i < RN) ? hist[i] : 0;
  }
  sh[tid] = s;
  __syncthreads();
  for (int off = SCAN_BLK / 2; off > 0; off >>= 1) {
    if (tid < off) sh[tid] += sh[tid + off];
    __syncthreads();
  }
  if (tid == 0) partials[blockIdx.x] = sh[0];
}

__global__ void scanB(int* __restrict__ partials, int nblk) {
  int acc = 0;
  for (int i = 0; i < nblk; ++i) {
    int v = partials[i];
    partials[i] = acc;
    acc += v;
  }
}

__global__ void scanC(const int* __restrict__ hist, const int* __restrict__ partials,
                      int* __restrict__ starts, int RN) {
  __shared__ int sh[SCAN_BLK];
  const int tid = threadIdx.x;
  int base = blockIdx.x * SCAN_CHUNK + tid * SCAN_ITEMS;
  int loc[SCAN_ITEMS];
  int s = 0;
  #pragma unroll
  for (int j = 0; j < SCAN_ITEMS; ++j) {
    int i = base + j;
    int v = (i < RN) ? hist[i] : 0;
    loc[j] = s;
    s += v;
  }
  sh[tid] = s;
  __syncthreads();
  for (int off = 1; off < SCAN_BLK; off <<= 1) {
    int v = (tid >= off) ? sh[tid - off] : 0;
    __syncthreads();
    sh[tid] += v;
    __syncthreads();
  }
  int texcl = (tid ? sh[tid - 1] : 0) + partials[blockIdx.x];
  #pragma unroll
  for (int j = 0; j < SCAN_ITEMS; ++j) {
    int i = base + j;
    if (i < RN) starts[i] = texcl + loc[j];
  }
}

__global__ void scatter_fill(const int* __restrict__ src, const int* __restrict__ tgt,
                             const int* __restrict__ et, int* __restrict__ starts,
                             int* __restrict__ sortedsrc, int E, int N) {
  int i = blockIdx.x * blockDim.x + threadIdx.x;
  int stride = gridDim.x * blockDim.x;
  for (; i < E; i += stride) {
    int key = et[i] * N + tgt[i];
    int pos = atomicAdd(&starts[key], 1);
    sortedsrc[pos] = src[i];
  }
}

// ---------------- converts (validated r7-r9) ----------------
__global__ void f32_to_bf16(const float* __restrict__ in, short* __restrict__ out, int n8) {
  int i = blockIdx.x * blockDim.x + threadIdx.x;
  int stride = gridDim.x * blockDim.x;
  for (; i < n8; i += stride) {
    const float* p = in + (size_t)i * 8;
    float4 a = *(const float4*)p;
    float4 b = *(const float4*)(p + 4);
    bf16x8 o;
    o[0] = f2bf(a.x); o[1] = f2bf(a.y); o[2] = f2bf(a.z); o[3] = f2bf(a.w);
    o[4] = f2bf(b.x); o[5] = f2bf(b.y); o[6] = f2bf(b.z); o[7] = f2bf(b.w);
    *(bf16x8*)(out + (size_t)i * 8) = o;
  }
}

// WtT[p][o][k] = (p<8 ? W[p][k][o] : root[k][o]) as bf16.
__global__ void w_conv(const float* __restrict__ W, const float* __restrict__ root,
                       short* __restrict__ WtT, int dout) {
  int total = 9 * dout * 128;
  int i = blockIdx.x * blockDim.x + threadIdx.x;
  int stride = gridDim.x * blockDim.x;
  for (; i < total; i += stride) {
    int p = i / (dout * 128);
    int rem = i - p * dout * 128;
    int o = rem >> 7;
    int k = rem & 127;
    float v = (p < 8) ? W[((size_t)p * 128 + k) * dout + o]
                      : root[(size_t)k * dout + o];
    WtT[i] = f2bf(v);
  }
}

// ---------------- panel-parallel fused RGCN layer ----------------
// Block = 256 threads (4 waves) owning 16 rows. Wave w: panels {w, w+4}
// (wave 0 also root). Lane: lr=lane&15 -> row, kg=(lane>>4)*8 -> k-slice (the
// MFMA A-frag slice). Partial C[16][DOUT] per wave in regs; LDS reduce with
// bias (+relu layer1). MFMA C/D: col=lane&15, row=(lane>>4)*4+reg (HW-validated).
template <int DOUT>
__device__ __forceinline__ void panel_mfma(
    int p, const short* __restrict__ Xb, const short* __restrict__ WtT,
    const int* __restrict__ sortedsrc, const int* __restrict__ starts,
    const int* __restrict__ hist, int row, bool rowok, int lr, int kg, int N,
    f32x4* acc) {
  constexpr int WC = DOUT / 16;
  float ga[4][8];
  #pragma unroll
  for (int kk = 0; kk < 4; ++kk)
    #pragma unroll
    for (int j = 0; j < 8; ++j) ga[kk][j] = 0.f;
  if (rowok) {
    const int key = p * N + row;
    const int end = starts[key];
    const int cnt = hist[key];
    for (int e = end - cnt; e < end; ++e) {
      int s = sortedsrc[e];
      const short* xp = Xb + (size_t)s * DIN + kg;
      #pragma unroll
      for (int kk = 0; kk < 4; ++kk) {
        bf16x8 v = *(const bf16x8*)(xp + kk * 32);
        #pragma unroll
        for (int j = 0; j < 8; ++j) ga[kk][j] += bf2f(v[j]);
      }
    }
    const float sc = 1.0f / fmaxf((float)cnt, 1.0f);
    #pragma unroll
    for (int kk = 0; kk < 4; ++kk)
      #pragma unroll
      for (int j = 0; j < 8; ++j) ga[kk][j] *= sc;
  }
  const short* Wp = WtT + (size_t)p * DOUT * 128;
  #pragma unroll
  for (int kk = 0; kk < 4; ++kk) {
    bf16x8 af;
    #pragma unroll
    for (int j = 0; j < 8; ++j) af[j] = f2bf(ga[kk][j]);
    #pragma unroll
    for (int ni = 0; ni < WC; ++ni) {
      bf16x8 b = *(const bf16x8*)(Wp + (size_t)(ni * 16 + lr) * 128 + kk * 32 + kg);
      acc[ni] = __builtin_amdgcn_mfma_f32_16x16x32_bf16(af, b, acc[ni], 0, 0, 0);
    }
  }
}

template <int DOUT, bool OUT_BF16_RELU>
__launch_bounds__(256, 4)
__global__ void rgcn_layer(const short* __restrict__ Xb, const short* __restrict__ WtT,
                           const int* __restrict__ sortedsrc, const int* __restrict__ starts,
                           const int* __restrict__ hist, const float* __restrict__ bias,
                           void* __restrict__ outv, int N) {
  constexpr int WC = DOUT / 16;
  constexpr int STR = DOUT + 4;  // padded f32 stride -> 2-way LDS conflicts (free)
  __shared__ __align__(16) float Cs[4][16][STR];
  const int tid = threadIdx.x;
  const int wid = tid >> 6;
  const int lane = tid & 63;
  const int lr = lane & 15;
  const int kg = (lane >> 4) * 8;
  const int row0 = blockIdx.x * 16;
  const int row = row0 + lr;
  const bool rowok = row < N;

  f32x4 acc[WC];
  #pragma unroll
  for (int ni = 0; ni < WC; ++ni) acc[ni] = (f32x4){0.f, 0.f, 0.f, 0.f};

  // gather panels: wave w -> rels w and w+4
  panel_mfma<DOUT>(wid, Xb, WtT, sortedsrc, starts, hist, row, rowok, lr, kg, N, acc);
  panel_mfma<DOUT>(wid + 4, Xb, WtT, sortedsrc, starts, hist, row, rowok, lr, kg, N, acc);

  // root panel on wave 0 (no gather: A = Xb row)
  if (wid == 0) {
    const short* Wp = WtT + (size_t)8 * DOUT * 128;
    #pragma unroll
    for (int kk = 0; kk < 4; ++kk) {
      bf16x8 af = {0, 0, 0, 0, 0, 0, 0, 0};
      if (rowok) af = *(const bf16x8*)(Xb + (size_t)row * DIN + kk * 32 + kg);
      #pragma unroll
      for (int ni = 0; ni < WC; ++ni) {
        bf16x8 b = *(const bf16x8*)(Wp + (size_t)(ni * 16 + lr) * 128 + kk * 32 + kg);
        acc[ni] = __builtin_amdgcn_mfma_f32_16x16x32_bf16(af, b, acc[ni], 0, 0, 0);
      }
    }
  }

  // write partial C to LDS: C[row=(lane>>4)*4+r][col=ni*16+lr]
  const int rbase = (lane >> 4) * 4;
  #pragma unroll
  for (int ni = 0; ni < WC; ++ni)
    #pragma unroll
    for (int r = 0; r < 4; ++r)
      Cs[wid][rbase + r][ni * 16 + lr] = acc[ni][r];
  __syncthreads();

  // reduce 4 partials + bias (+relu), store. 16*DOUT elems, float4 per thread.
  constexpr int TOT = 16 * DOUT;
  #pragma unroll
  for (int base = tid * 4; base < TOT; base += 256 * 4) {
    const int rrow = base / DOUT;
    const int col = base % DOUT;
    float4 s = *(const float4*)&Cs[0][rrow][col];
    #pragma unroll
    for (int w = 1; w < 4; ++w) {
      float4 t = *(const float4*)&Cs[w][rrow][col];
      s.x += t.x; s.y += t.y; s.z += t.z; s.w += t.w;
    }
    float4 bv = *(const float4*)(bias + col);
    s.x += bv.x; s.y += bv.y; s.z += bv.z; s.w += bv.w;
    const int rr = row0 + rrow;
    if (rr >= N) continue;
    if (OUT_BF16_RELU) {
      short4 o;
      o.x = f2bf(fmaxf(s.x, 0.f)); o.y = f2bf(fmaxf(s.y, 0.f));
      o.z = f2bf(fmaxf(s.z, 0.f)); o.w = f2bf(fmaxf(s.w, 0.f));
      *(short4*)((short*)outv + (size_t)rr * DOUT + col) = o;
    } else {
      *(float4*)((float*)outv + (size_t)rr * DOUT + col) = s;
    }
  }
}

// ---------------- host ----------------
extern "C" void kernel_launch(void* const* d_in, const int* in_sizes, int n_in,
                              void* d_out, int out_size, void* d_ws, size_t ws_size,
                              hipStream_t stream) {
  const float* x     = (const float*)d_in[0];
  const int*   ei    = (const int*)d_in[1];
  const int*   et    = (const int*)d_in[2];
  const float* W1    = (const float*)d_in[3];
  const float* root1 = (const float*)d_in[4];
  const float* b1    = (const float*)d_in[5];
  const float* W2    = (const float*)d_in[6];
  const float* root2 = (const float*)d_in[7];
  const float* b2    = (const float*)d_in[8];
  float* out = (float*)d_out;

  const int N = in_sizes[0] / DIN;
  const int E = in_sizes[1] / 2;
  const int* src = ei;
  const int* tgt = ei + E;
  const int RN = N * NREL;

  // ws: hist | starts | partials | sortedsrc | xb | hb | WtT1 | WtT2  (~65 MB)
  char* ws = (char*)d_ws;
  size_t off = 0;
  auto take = [&](size_t bytes) { char* p = ws + off; off += (bytes + 255) & ~(size_t)255; return p; };
  int*   hist      = (int*)take((size_t)RN * 4);
  int*   starts    = (int*)take((size_t)RN * 4);
  int*   partials  = (int*)take(1024);
  int*   sortedsrc = (int*)take((size_t)E * 4);
  short* xb        = (short*)take((size_t)N * DIN * 2);
  short* hb        = (short*)take((size_t)N * DIN * 2);
  short* WtT1      = (short*)take((size_t)9 * 128 * 128 * 2);
  short* WtT2      = (short*)take((size_t)9 * 64 * 128 * 2);

  const int gbl = (N + 15) / 16;   // layer blocks (16 rows, 4 panel-parallel waves)
  const int nblkA = (RN + SCAN_CHUNK - 1) / SCAN_CHUNK;

  // ---- CSR build (once; graph shared by both layers) ----
  zero_ints<<<(RN / 4 + 255) / 256, 256, 0, stream>>>((int4*)hist, RN / 4);
  hist_kernel<<<2048, 256, 0, stream>>>(tgt, et, hist, E, N);
  scanA<<<nblkA, SCAN_BLK, 0, stream>>>(hist, partials, RN);
  scanB<<<1, 1, 0, stream>>>(partials, nblkA);
  scanC<<<nblkA, SCAN_BLK, 0, stream>>>(hist, partials, starts, RN);
  scatter_fill<<<2048, 256, 0, stream>>>(src, tgt, et, starts, sortedsrc, E, N);

  // ---- weight convert+transpose, x -> bf16 ----
  w_conv<<<576, 256, 0, stream>>>(W1, root1, WtT1, 128);
  w_conv<<<288, 256, 0, stream>>>(W2, root2, WtT2, 64);
  f32_to_bf16<<<2048, 256, 0, stream>>>(x, xb, N * DIN / 8);

  // ---- fused layers (panel-parallel) ----
  rgcn_layer<128, true><<<gbl, 256, 0, stream>>>(
      xb, WtT1, sortedsrc, starts, hist, b1, hb, N);
  rgcn_layer<64, false><<<gbl, 256, 0, stream>>>(
      hb, WtT2, sortedsrc, starts, hist, b2, out, N);
}

// Round 12
// 765.304 us; speedup vs baseline: 9.1453x; 1.0363x over previous
//
#include <hip/hip_runtime.h>
#include <cstdint>
#include <cstddef>

// RGCN 2-layer forward, round 12: MLP-unrolled panel-parallel fused layer.
// r11 evidence: layer1 299us, FETCH ~200MB (8x xb footprint, random L2 misses),
// implied miss-BW 776 GB/s, per-wave residency 42us => queueing, not raw latency.
// A/B this round: (1) segment walk unrolled x2 (10 outstanding loads/lane vs 5),
// (2) root panel split across 4 waves (kk=wid). If time drops ~2x: was MLP-bound.
// If flat with BW pinned ~0.8 TB/s: random-miss service ceiling confirmed ->
// round 13 = chunked gather. CSR build untouched.

#define DIN 128
#define NREL 8
#define SCAN_BLK 256
#define SCAN_ITEMS 16
#define SCAN_CHUNK (SCAN_BLK * SCAN_ITEMS)

typedef short bf16x8 __attribute__((ext_vector_type(8)));
typedef float f32x4 __attribute__((ext_vector_type(4)));

__device__ inline float bf2f(short s) {
  return __uint_as_float(((unsigned int)(unsigned short)s) << 16);
}
__device__ inline short f2bf(float f) {  // RTNE
  unsigned int u = __float_as_uint(f);
  unsigned int r = (u + 0x7FFFu + ((u >> 16) & 1u)) >> 16;
  return (short)r;
}

// ---------------- CSR build (validated r7-r11) ----------------
__global__ void zero_ints(int4* __restrict__ p, int n4) {
  int i = blockIdx.x * blockDim.x + threadIdx.x;
  int stride = gridDim.x * blockDim.x;
  int4 z; z.x = z.y = z.z = z.w = 0;
  for (; i < n4; i += stride) p[i] = z;
}

__global__ void hist_kernel(const int* __restrict__ tgt, const int* __restrict__ et,
                            int* __restrict__ hist, int E, int N) {
  int i = blockIdx.x * blockDim.x + threadIdx.x;
  int stride = gridDim.x * blockDim.x;
  for (; i < E; i += stride)
    atomicAdd(&hist[et[i] * N + tgt[i]], 1);
}

__global__ void scanA(const int* __restrict__ hist, int* __restrict__ partials, int RN) {
  __shared__ int sh[SCAN_BLK];
  const int tid = threadIdx.x;
  int base = blockIdx.x * SCAN_CHUNK + tid * SCAN_ITEMS;
  int s = 0;
  #pragma unroll
  for (int j = 0; j < SCAN_ITEMS; ++j) {
    int i = base + j;
    s += (i < RN) ? hist[i] : 0;
  }
  sh[tid] = s;
  __syncthreads();
  for (int off = SCAN_BLK / 2; off > 0; off >>= 1) {
    if (tid < off) sh[tid] += sh[tid + off];
    __syncthreads();
  }
  if (tid == 0) partials[blockIdx.x] = sh[0];
}

__global__ void scanB(int* __restrict__ partials, int nblk) {
  int acc = 0;
  for (int i = 0; i < nblk; ++i) {
    int v = partials[i];
    partials[i] = acc;
    acc += v;
  }
}

__global__ void scanC(const int* __restrict__ hist, const int* __restrict__ partials,
                      int* __restrict__ starts, int RN) {
  __shared__ int sh[SCAN_BLK];
  const int tid = threadIdx.x;
  int base = blockIdx.x * SCAN_CHUNK + tid * SCAN_ITEMS;
  int loc[SCAN_ITEMS];
  int s = 0;
  #pragma unroll
  for (int j = 0; j < SCAN_ITEMS; ++j) {
    int i = base + j;
    int v = (i < RN) ? hist[i] : 0;
    loc[j] = s;
    s += v;
  }
  sh[tid] = s;
  __syncthreads();
  for (int off = 1; off < SCAN_BLK; off <<= 1) {
    int v = (tid >= off) ? sh[tid - off] : 0;
    __syncthreads();
    sh[tid] += v;
    __syncthreads();
  }
  int texcl = (tid ? sh[tid - 1] : 0) + partials[blockIdx.x];
  #pragma unroll
  for (int j = 0; j < SCAN_ITEMS; ++j) {
    int i = base + j;
    if (i < RN) starts[i] = texcl + loc[j];
  }
}

__global__ void scatter_fill(const int* __restrict__ src, const int* __restrict__ tgt,
                             const int* __restrict__ et, int* __restrict__ starts,
                             int* __restrict__ sortedsrc, int E, int N) {
  int i = blockIdx.x * blockDim.x + threadIdx.x;
  int stride = gridDim.x * blockDim.x;
  for (; i < E; i += stride) {
    int key = et[i] * N + tgt[i];
    int pos = atomicAdd(&starts[key], 1);
    sortedsrc[pos] = src[i];
  }
}

// ---------------- converts (validated r7-r11) ----------------
__global__ void f32_to_bf16(const float* __restrict__ in, short* __restrict__ out, int n8) {
  int i = blockIdx.x * blockDim.x + threadIdx.x;
  int stride = gridDim.x * blockDim.x;
  for (; i < n8; i += stride) {
    const float* p = in + (size_t)i * 8;
    float4 a = *(const float4*)p;
    float4 b = *(const float4*)(p + 4);
    bf16x8 o;
    o[0] = f2bf(a.x); o[1] = f2bf(a.y); o[2] = f2bf(a.z); o[3] = f2bf(a.w);
    o[4] = f2bf(b.x); o[5] = f2bf(b.y); o[6] = f2bf(b.z); o[7] = f2bf(b.w);
    *(bf16x8*)(out + (size_t)i * 8) = o;
  }
}

// WtT[p][o][k] = (p<8 ? W[p][k][o] : root[k][o]) as bf16.
__global__ void w_conv(const float* __restrict__ W, const float* __restrict__ root,
                       short* __restrict__ WtT, int dout) {
  int total = 9 * dout * 128;
  int i = blockIdx.x * blockDim.x + threadIdx.x;
  int stride = gridDim.x * blockDim.x;
  for (; i < total; i += stride) {
    int p = i / (dout * 128);
    int rem = i - p * dout * 128;
    int o = rem >> 7;
    int k = rem & 127;
    float v = (p < 8) ? W[((size_t)p * 128 + k) * dout + o]
                      : root[(size_t)k * dout + o];
    WtT[i] = f2bf(v);
  }
}

// ---------------- panel gather+MFMA, 2-edge unrolled ----------------
template <int DOUT>
__device__ __forceinline__ void panel_mfma(
    int p, const short* __restrict__ Xb, const short* __restrict__ WtT,
    const int* __restrict__ sortedsrc, const int* __restrict__ starts,
    const int* __restrict__ hist, int row, bool rowok, int lr, int kg, int N,
    f32x4* acc) {
  constexpr int WC = DOUT / 16;
  float ga[4][8];
  #pragma unroll
  for (int kk = 0; kk < 4; ++kk)
    #pragma unroll
    for (int j = 0; j < 8; ++j) ga[kk][j] = 0.f;
  if (rowok) {
    const int key = p * N + row;
    const int end = starts[key];
    const int cnt = hist[key];
    int e = end - cnt;
    // 2-edge pipeline: 2 sortedsrc + 8 row-slice loads in flight per lane
    for (; e + 2 <= end; e += 2) {
      int s0 = sortedsrc[e];
      int s1 = sortedsrc[e + 1];
      const short* p0 = Xb + (size_t)s0 * DIN + kg;
      const short* p1 = Xb + (size_t)s1 * DIN + kg;
      bf16x8 v0[4], v1[4];
      #pragma unroll
      for (int kk = 0; kk < 4; ++kk) {
        v0[kk] = *(const bf16x8*)(p0 + kk * 32);
        v1[kk] = *(const bf16x8*)(p1 + kk * 32);
      }
      #pragma unroll
      for (int kk = 0; kk < 4; ++kk)
        #pragma unroll
        for (int j = 0; j < 8; ++j)
          ga[kk][j] += bf2f(v0[kk][j]) + bf2f(v1[kk][j]);
    }
    if (e < end) {  // tail edge
      int s0 = sortedsrc[e];
      const short* p0 = Xb + (size_t)s0 * DIN + kg;
      #pragma unroll
      for (int kk = 0; kk < 4; ++kk) {
        bf16x8 v = *(const bf16x8*)(p0 + kk * 32);
        #pragma unroll
        for (int j = 0; j < 8; ++j) ga[kk][j] += bf2f(v[j]);
      }
    }
    const float sc = 1.0f / fmaxf((float)cnt, 1.0f);
    #pragma unroll
    for (int kk = 0; kk < 4; ++kk)
      #pragma unroll
      for (int j = 0; j < 8; ++j) ga[kk][j] *= sc;
  }
  const short* Wp = WtT + (size_t)p * DOUT * 128;
  #pragma unroll
  for (int kk = 0; kk < 4; ++kk) {
    bf16x8 af;
    #pragma unroll
    for (int j = 0; j < 8; ++j) af[j] = f2bf(ga[kk][j]);
    #pragma unroll
    for (int ni = 0; ni < WC; ++ni) {
      bf16x8 b = *(const bf16x8*)(Wp + (size_t)(ni * 16 + lr) * 128 + kk * 32 + kg);
      acc[ni] = __builtin_amdgcn_mfma_f32_16x16x32_bf16(af, b, acc[ni], 0, 0, 0);
    }
  }
}

// ---------------- panel-parallel fused RGCN layer ----------------
// Block = 4 waves sharing 16 rows. Wave w: gather panels {w, w+4} + root k-block
// kk=w (balanced). Partial C in regs; LDS reduce (+bias/relu).
template <int DOUT, bool OUT_BF16_RELU>
__launch_bounds__(256, 4)
__global__ void rgcn_layer(const short* __restrict__ Xb, const short* __restrict__ WtT,
                           const int* __restrict__ sortedsrc, const int* __restrict__ starts,
                           const int* __restrict__ hist, const float* __restrict__ bias,
                           void* __restrict__ outv, int N) {
  constexpr int WC = DOUT / 16;
  constexpr int STR = DOUT + 4;  // padded f32 stride
  __shared__ __align__(16) float Cs[4][16][STR];
  const int tid = threadIdx.x;
  const int wid = tid >> 6;
  const int lane = tid & 63;
  const int lr = lane & 15;
  const int kg = (lane >> 4) * 8;
  const int row0 = blockIdx.x * 16;
  const int row = row0 + lr;
  const bool rowok = row < N;

  f32x4 acc[WC];
  #pragma unroll
  for (int ni = 0; ni < WC; ++ni) acc[ni] = (f32x4){0.f, 0.f, 0.f, 0.f};

  // gather panels: wave w -> rels w and w+4
  panel_mfma<DOUT>(wid, Xb, WtT, sortedsrc, starts, hist, row, rowok, lr, kg, N, acc);
  panel_mfma<DOUT>(wid + 4, Xb, WtT, sortedsrc, starts, hist, row, rowok, lr, kg, N, acc);

  // root panel: wave w takes k-block kk=wid (balanced across waves)
  {
    const short* Wp = WtT + (size_t)8 * DOUT * 128;
    const int kk = wid;
    bf16x8 af = {0, 0, 0, 0, 0, 0, 0, 0};
    if (rowok) af = *(const bf16x8*)(Xb + (size_t)row * DIN + kk * 32 + kg);
    #pragma unroll
    for (int ni = 0; ni < WC; ++ni) {
      bf16x8 b = *(const bf16x8*)(Wp + (size_t)(ni * 16 + lr) * 128 + kk * 32 + kg);
      acc[ni] = __builtin_amdgcn_mfma_f32_16x16x32_bf16(af, b, acc[ni], 0, 0, 0);
    }
  }

  // write partial C to LDS: C[row=(lane>>4)*4+r][col=ni*16+lr]
  const int rbase = (lane >> 4) * 4;
  #pragma unroll
  for (int ni = 0; ni < WC; ++ni)
    #pragma unroll
    for (int r = 0; r < 4; ++r)
      Cs[wid][rbase + r][ni * 16 + lr] = acc[ni][r];
  __syncthreads();

  // reduce 4 partials + bias (+relu), store. 16*DOUT elems, float4 per thread.
  constexpr int TOT = 16 * DOUT;
  #pragma unroll
  for (int base = tid * 4; base < TOT; base += 256 * 4) {
    const int rrow = base / DOUT;
    const int col = base % DOUT;
    float4 s = *(const float4*)&Cs[0][rrow][col];
    #pragma unroll
    for (int w = 1; w < 4; ++w) {
      float4 t = *(const float4*)&Cs[w][rrow][col];
      s.x += t.x; s.y += t.y; s.z += t.z; s.w += t.w;
    }
    float4 bv = *(const float4*)(bias + col);
    s.x += bv.x; s.y += bv.y; s.z += bv.z; s.w += bv.w;
    const int rr = row0 + rrow;
    if (rr >= N) continue;
    if (OUT_BF16_RELU) {
      short4 o;
      o.x = f2bf(fmaxf(s.x, 0.f)); o.y = f2bf(fmaxf(s.y, 0.f));
      o.z = f2bf(fmaxf(s.z, 0.f)); o.w = f2bf(fmaxf(s.w, 0.f));
      *(short4*)((short*)outv + (size_t)rr * DOUT + col) = o;
    } else {
      *(float4*)((float*)outv + (size_t)rr * DOUT + col) = s;
    }
  }
}

// ---------------- host ----------------
extern "C" void kernel_launch(void* const* d_in, const int* in_sizes, int n_in,
                              void* d_out, int out_size, void* d_ws, size_t ws_size,
                              hipStream_t stream) {
  const float* x     = (const float*)d_in[0];
  const int*   ei    = (const int*)d_in[1];
  const int*   et    = (const int*)d_in[2];
  const float* W1    = (const float*)d_in[3];
  const float* root1 = (const float*)d_in[4];
  const float* b1    = (const float*)d_in[5];
  const float* W2    = (const float*)d_in[6];
  const float* root2 = (const float*)d_in[7];
  const float* b2    = (const float*)d_in[8];
  float* out = (float*)d_out;

  const int N = in_sizes[0] / DIN;
  const int E = in_sizes[1] / 2;
  const int* src = ei;
  const int* tgt = ei + E;
  const int RN = N * NREL;

  // ws: hist | starts | partials | sortedsrc | xb | hb | WtT1 | WtT2  (~65 MB)
  char* ws = (char*)d_ws;
  size_t off = 0;
  auto take = [&](size_t bytes) { char* p = ws + off; off += (bytes + 255) & ~(size_t)255; return p; };
  int*   hist      = (int*)take((size_t)RN * 4);
  int*   starts    = (int*)take((size_t)RN * 4);
  int*   partials  = (int*)take(1024);
  int*   sortedsrc = (int*)take((size_t)E * 4);
  short* xb        = (short*)take((size_t)N * DIN * 2);
  short* hb        = (short*)take((size_t)N * DIN * 2);
  short* WtT1      = (short*)take((size_t)9 * 128 * 128 * 2);
  short* WtT2      = (short*)take((size_t)9 * 64 * 128 * 2);

  const int gbl = (N + 15) / 16;   // layer blocks (16 rows, 4 panel-parallel waves)
  const int nblkA = (RN + SCAN_CHUNK - 1) / SCAN_CHUNK;

  // ---- CSR build (once; graph shared by both layers) ----
  zero_ints<<<(RN / 4 + 255) / 256, 256, 0, stream>>>((int4*)hist, RN / 4);
  hist_kernel<<<2048, 256, 0, stream>>>(tgt, et, hist, E, N);
  scanA<<<nblkA, SCAN_BLK, 0, stream>>>(hist, partials, RN);
  scanB<<<1, 1, 0, stream>>>(partials, nblkA);
  scanC<<<nblkA, SCAN_BLK, 0, stream>>>(hist, partials, starts, RN);
  scatter_fill<<<2048, 256, 0, stream>>>(src, tgt, et, starts, sortedsrc, E, N);

  // ---- weight convert+transpose, x -> bf16 ----
  w_conv<<<576, 256, 0, stream>>>(W1, root1, WtT1, 128);
  w_conv<<<288, 256, 0, stream>>>(W2, root2, WtT2, 64);
  f32_to_bf16<<<2048, 256, 0, stream>>>(x, xb, N * DIN / 8);

  // ---- fused layers (panel-parallel, MLP-unrolled) ----
  rgcn_layer<128, true><<<gbl, 256, 0, stream>>>(
      xb, WtT1, sortedsrc, starts, hist, b1, hb, N);
  rgcn_layer<64, false><<<gbl, 256, 0, stream>>>(
      hb, WtT2, sortedsrc, starts, hist, b2, out, N);
}